// Round 13
// baseline (558.658 us; speedup 1.0000x reference)
//
#include <hip/hip_runtime.h>

#define B_   256
#define L_   200
#define D_   256
#define H_   8
#define DK_  32
#define IN_  64
#define HID_ 128
#define LAM_ 0.01f

using f32x4 = __attribute__((ext_vector_type(4))) float;
using bf16x8 = __attribute__((ext_vector_type(8))) short;

__device__ inline unsigned short bf16_rn(float f) {
  unsigned int u = __float_as_uint(f);
  return (unsigned short)((u + 0x7fffu + ((u >> 16) & 1u)) >> 16);
}

__device__ inline f32x4 mfma16(f32x4 c, bf16x8 a, bf16x8 b) {
  return __builtin_amdgcn_mfma_f32_16x16x32_bf16(a, b, c, 0, 0, 0);
}

// ---------------- cast x (f32 -> bf16), 8 elems/thread ----------------
__global__ __launch_bounds__(256) void cast_x_k(const float* __restrict__ x,
                                                unsigned short* __restrict__ xb) {
  long i = (long)blockIdx.x * 256 + threadIdx.x;
  const float4* px = (const float4*)x;
  float4 a = px[2 * i], b = px[2 * i + 1];
  unsigned int w0 = bf16_rn(a.x) | ((unsigned int)bf16_rn(a.y) << 16);
  unsigned int w1 = bf16_rn(a.z) | ((unsigned int)bf16_rn(a.w) << 16);
  unsigned int w2 = bf16_rn(b.x) | ((unsigned int)bf16_rn(b.y) << 16);
  unsigned int w3 = bf16_rn(b.z) | ((unsigned int)bf16_rn(b.w) << 16);
  *(uint4*)(xb + 8 * i) = make_uint4(w0, w1, w2, w3);
}

// ---------------- hypernetwork h1 -> bf16 [b][j] ----------------
__global__ void hyper_h1(const float* __restrict__ ue, const float* __restrict__ fc1w,
                         const float* __restrict__ fc1b, unsigned short* __restrict__ h1b) {
  int b = blockIdx.x, j = threadIdx.x;
  __shared__ float us[IN_];
  if (j < IN_) us[j] = ue[b * IN_ + j];
  __syncthreads();
  float acc = fc1b[j];
#pragma unroll
  for (int i = 0; i < IN_; ++i) acc = fmaf(us[i], fc1w[i * HID_ + j], acc);
  h1b[b * HID_ + j] = bf16_rn(1.f / (1.f + __expf(-acc)));
}

// ---------------- transpose+cast Wk/Wv/Wo -> [n][k] bf16 ----------------
__global__ void prep_wt(const float* __restrict__ Wk, const float* __restrict__ Wv,
                        const float* __restrict__ Wo, unsigned short* __restrict__ wkT,
                        unsigned short* __restrict__ wvT, unsigned short* __restrict__ woT) {
  const float* W = blockIdx.y == 0 ? Wk : (blockIdx.y == 1 ? Wv : Wo);
  unsigned short* O = blockIdx.y == 0 ? wkT : (blockIdx.y == 1 ? wvT : woT);
  int n = blockIdx.x, k = threadIdx.x;
  O[n * D_ + k] = bf16_rn(W[k * D_ + n]);
}

// ---- prep_fc2: fc2wT[n][j] = bf16(LAM*fc2w[j][de]), n=(de&255)*256+(de>>8) ----
// also bias2[n] = LAM*fc2b[de] + basew[de]
__global__ __launch_bounds__(256) void prep_fc2(const float* __restrict__ fc2w,
                                                const float* __restrict__ fc2b,
                                                const float* __restrict__ basew,
                                                unsigned short* __restrict__ fc2wT,
                                                float* __restrict__ bias2) {
  __shared__ float t[32][33];
  int de0 = blockIdx.x * 32, j0 = blockIdx.y * 32;
  int tid = threadIdx.x;
  {
    int jj = tid >> 3, dd4 = (tid & 7) * 4;
    float4 v = *(const float4*)(fc2w + (long)(j0 + jj) * (D_ * D_) + de0 + dd4);
    t[jj][dd4] = v.x; t[jj][dd4 + 1] = v.y; t[jj][dd4 + 2] = v.z; t[jj][dd4 + 3] = v.w;
  }
  __syncthreads();
  int dd = tid >> 3, jj4 = (tid & 7) * 4;
  int de = de0 + dd;
  int n = (de & 255) * 256 + (de >> 8);  // n = e*256 + d
  unsigned short r0 = bf16_rn(LAM_ * t[jj4 + 0][dd]);
  unsigned short r1 = bf16_rn(LAM_ * t[jj4 + 1][dd]);
  unsigned short r2 = bf16_rn(LAM_ * t[jj4 + 2][dd]);
  unsigned short r3 = bf16_rn(LAM_ * t[jj4 + 3][dd]);
  unsigned int lo = r0 | ((unsigned int)r1 << 16), hi = r2 | ((unsigned int)r3 << 16);
  *(uint2*)(fc2wT + (long)n * HID_ + j0 + jj4) = make_uint2(lo, hi);
  if (blockIdx.y == 0 && (tid & 7) == 0)
    bias2[n] = LAM_ * fc2b[de] + basew[de];
}

// ---------------- unified GEMM: tile 64 rows x 256 cols, 4 waves, BK=32 ----------------
// C[b][row][col] = sum_k A[b][row][k] * Wt[b][col][k] + bias[b][col]
// OUT_MODE 0: f32, 1: bf16, 2: bf16 transposed (C[b][col][row], ldC given, width 224)
template <int OUT_MODE, int KSTEPS>
__global__ __launch_bounds__(256) void gemm64x256(
    const unsigned short* __restrict__ A, const unsigned short* __restrict__ Wt,
    const float* __restrict__ bias, void* __restrict__ Cout,
    int Mvalid, int ldA, int ldW, int ldC,
    long bsA, long bsW, long bsBias, long bsC, int nMt, int nB) {
  __shared__ unsigned short ldsA[64 * 40];
  __shared__ unsigned short ldsB[256 * 40];
  int id = blockIdx.x;
  int b, mt;
  if (nB > 1) {
    int xcd = id & 7, t = id >> 3;
    b = (t / nMt) * 8 + xcd;
    mt = t % nMt;
  } else {
    b = 0;
    mt = id;
  }
  int row0 = mt * 64;
  int tid = threadIdx.x, lane = tid & 63, w = tid >> 6;
  int c = lane & 15, g = lane >> 4;
  const unsigned short* Ab = A + (long)b * bsA;
  const unsigned short* Wb = Wt + (long)b * bsW;
  int sr = tid >> 2, sk = (tid & 3) * 8;
  long arow = row0 + sr;
  if (arow >= Mvalid) arow = Mvalid - 1;
  f32x4 acc[4][4];
#pragma unroll
  for (int mi = 0; mi < 4; ++mi)
#pragma unroll
    for (int ni = 0; ni < 4; ++ni) acc[mi][ni] = (f32x4){0.f, 0.f, 0.f, 0.f};

  for (int kt = 0; kt < KSTEPS; ++kt) {
    int k0 = kt * 32;
    uint4 av = *(const uint4*)(Ab + arow * ldA + k0 + sk);
    uint4 bv[4];
#pragma unroll
    for (int i = 0; i < 4; ++i)
      bv[i] = *(const uint4*)(Wb + (long)(sr + i * 64) * ldW + k0 + sk);
    __syncthreads();
    *(uint4*)(&ldsA[sr * 40 + sk]) = av;
#pragma unroll
    for (int i = 0; i < 4; ++i) *(uint4*)(&ldsB[(sr + i * 64) * 40 + sk]) = bv[i];
    __syncthreads();
    bf16x8 af[4], bf[4];
#pragma unroll
    for (int mi = 0; mi < 4; ++mi) af[mi] = *(const bf16x8*)(&ldsA[(mi * 16 + c) * 40 + g * 8]);
#pragma unroll
    for (int ni = 0; ni < 4; ++ni)
      bf[ni] = *(const bf16x8*)(&ldsB[(w * 64 + ni * 16 + c) * 40 + g * 8]);
#pragma unroll
    for (int mi = 0; mi < 4; ++mi)
#pragma unroll
      for (int ni = 0; ni < 4; ++ni) acc[mi][ni] = mfma16(acc[mi][ni], af[mi], bf[ni]);
  }

  if (OUT_MODE != 2) {
#pragma unroll
    for (int mi = 0; mi < 4; ++mi)
#pragma unroll
      for (int ni = 0; ni < 4; ++ni) {
        int col = w * 64 + ni * 16 + c;
        float bi = bias[b * bsBias + col];
#pragma unroll
        for (int j = 0; j < 4; ++j) {
          int row = row0 + mi * 16 + g * 4 + j;
          if (row < Mvalid) {
            float val = acc[mi][ni][j] + bi;
            long off = (long)b * bsC + (long)row * ldC + col;
            if (OUT_MODE == 1)
              ((unsigned short*)Cout)[off] = bf16_rn(val);
            else
              ((float*)Cout)[off] = val;
          }
        }
      }
  } else {
    // transposed bf16 epilogue via LDS bounce: C[b][col][row]
    __syncthreads();
#pragma unroll
    for (int h = 0; h < 2; ++h) {
#pragma unroll
      for (int mi2 = 0; mi2 < 2; ++mi2) {
        int mi = h * 2 + mi2;
#pragma unroll
        for (int ni = 0; ni < 4; ++ni) {
          int col = w * 64 + ni * 16 + c;
          float bi = bias[col];
#pragma unroll
          for (int j = 0; j < 4; ++j)
            ldsB[col * 40 + mi2 * 16 + g * 4 + j] = bf16_rn(acc[mi][ni][j] + bi);
        }
      }
      __syncthreads();
      int m0 = row0 + h * 32;
      if (m0 < 224) {
        int col = tid;
        unsigned short* dst = (unsigned short*)Cout + (long)b * bsC + (long)col * ldC + m0;
        uint4 q0 = *(const uint4*)(&ldsB[col * 40 + 0]);
        uint4 q1 = *(const uint4*)(&ldsB[col * 40 + 8]);
        uint4 q2 = *(const uint4*)(&ldsB[col * 40 + 16]);
        uint4 q3 = *(const uint4*)(&ldsB[col * 40 + 24]);
        *(uint4*)(dst + 0) = q0;
        *(uint4*)(dst + 8) = q1;
        *(uint4*)(dst + 16) = q2;
        *(uint4*)(dst + 24) = q3;
      }
      __syncthreads();
    }
  }
}

// ---------------- fused causal attention, v2 ----------------
// grid (4 qtiles, H, B). LDS: sK[224][40] aliased with sP[64][232]; sV[32][232].
__global__ __launch_bounds__(256) void attn_k(const unsigned short* __restrict__ q,
                                              const unsigned short* __restrict__ k,
                                              const unsigned short* __restrict__ vT,
                                              unsigned short* __restrict__ o) {
  __shared__ unsigned short smem[22272];  // 44544 B
  unsigned short* sKP = smem;             // sK: m*40+d (224x40) / sP: l*232+m (64x232)
  unsigned short* sV = smem + 14848;      // d*232+m (32x232)
  int b = blockIdx.z, h = blockIdx.y, q0 = blockIdx.x * 64;
  int tid = threadIdx.x, lane = tid & 63, w = tid >> 6, c = lane & 15, g = lane >> 4;
  long base = ((long)b * L_) * D_ + h * DK_;
  long vbase = ((long)b * D_ + h * DK_) * 224;

  int nfr = min(13, (q0 + 64) >> 4);
  int nkb = min(7, (q0 + 64) >> 5);

  for (int idx = tid; idx < 896; idx += 256) {
    int m = idx >> 2, dd = idx & 3;
    int mc = m < L_ ? m : L_ - 1;
    *(uint4*)(&sKP[m * 40 + dd * 8]) = *(const uint4*)(k + base + (long)mc * D_ + dd * 8);
  }
  for (int idx = tid; idx < 896; idx += 256) {
    int d = idx / 28, mc8 = (idx % 28) * 8;
    *(uint4*)(&sV[d * 232 + mc8]) = *(const uint4*)(vT + vbase + (long)d * 224 + mc8);
  }
  int ql = q0 + w * 16 + c;
  if (ql >= L_) ql = L_ - 1;
  bf16x8 qf = *(const bf16x8*)(q + base + (long)ql * D_ + g * 8);
  __syncthreads();

  f32x4 zero = {0.f, 0.f, 0.f, 0.f};
  f32x4 s[13];
#pragma unroll
  for (int mf = 0; mf < 13; ++mf)
    if (mf < nfr) {
      bf16x8 kf = *(const bf16x8*)(&sKP[(mf * 16 + c) * 40 + g * 8]);
      s[mf] = mfma16(zero, qf, kf);
    }
  const float scale = 0.17677669529663687f;  // 1/sqrt(32)
  int lg = q0 + w * 16 + g * 4;
#pragma unroll
  for (int mf = 0; mf < 13; ++mf)
    if (mf < nfr) {
      int m = mf * 16 + c;
#pragma unroll
      for (int j = 0; j < 4; ++j) {
        bool ok = (m <= lg + j) && (m < L_);
        s[mf][j] = ok ? s[mf][j] * scale : -1e9f;
      }
    }
  float mx[4], sm[4], inv[4];
#pragma unroll
  for (int j = 0; j < 4; ++j) {
    float m0 = -1e9f;
#pragma unroll
    for (int mf = 0; mf < 13; ++mf)
      if (mf < nfr) m0 = fmaxf(m0, s[mf][j]);
    m0 = fmaxf(m0, __shfl_xor(m0, 1));
    m0 = fmaxf(m0, __shfl_xor(m0, 2));
    m0 = fmaxf(m0, __shfl_xor(m0, 4));
    m0 = fmaxf(m0, __shfl_xor(m0, 8));
    mx[j] = m0;
  }
#pragma unroll
  for (int j = 0; j < 4; ++j) {
    float ss = 0.f;
#pragma unroll
    for (int mf = 0; mf < 13; ++mf)
      if (mf < nfr) {
        float p = __expf(s[mf][j] - mx[j]);
        s[mf][j] = p;
        ss += p;
      }
    ss += __shfl_xor(ss, 1);
    ss += __shfl_xor(ss, 2);
    ss += __shfl_xor(ss, 4);
    ss += __shfl_xor(ss, 8);
    sm[j] = ss;
    inv[j] = 1.f / ss;
  }
  __syncthreads();  // all K reads done; sP may overwrite sK
  int row = w * 16 + g * 4;
#pragma unroll
  for (int mf = 0; mf < 14; ++mf) {
    if (mf < nfr) {
#pragma unroll
      for (int j = 0; j < 4; ++j) sKP[(row + j) * 232 + mf * 16 + c] = bf16_rn(s[mf][j]);
    } else if (mf < 2 * nkb) {
#pragma unroll
      for (int j = 0; j < 4; ++j) sKP[(row + j) * 232 + mf * 16 + c] = 0;
    }
  }
  __syncthreads();

  f32x4 oa[2];
  oa[0] = zero;
  oa[1] = zero;
#pragma unroll
  for (int kb = 0; kb < 7; ++kb)
    if (kb < nkb) {
      bf16x8 pf = *(const bf16x8*)(&sKP[(w * 16 + c) * 232 + kb * 32 + g * 8]);
#pragma unroll
      for (int nf = 0; nf < 2; ++nf) {
        bf16x8 vf = *(const bf16x8*)(&sV[(nf * 16 + c) * 232 + kb * 32 + g * 8]);
        oa[nf] = mfma16(oa[nf], pf, vf);
      }
    }
#pragma unroll
  for (int nf = 0; nf < 2; ++nf)
#pragma unroll
    for (int j = 0; j < 4; ++j) {
      int l = q0 + w * 16 + g * 4 + j;
      if (l < L_) o[base + (long)l * D_ + nf * 16 + c] = bf16_rn(oa[nf][j] * inv[j]);
    }
}

extern "C" void kernel_launch(void* const* d_in, const int* in_sizes, int n_in,
                              void* d_out, int out_size, void* d_ws, size_t ws_size,
                              hipStream_t stream) {
  const float* x = (const float*)d_in[0];
  const float* ue = (const float*)d_in[1];
  const float* fc1w = (const float*)d_in[2];
  const float* fc1b = (const float*)d_in[3];
  const float* fc2w = (const float*)d_in[4];
  const float* fc2b = (const float*)d_in[5];
  const float* bw = (const float*)d_in[6];
  const float* bq = (const float*)d_in[7];
  const float* Wk = (const float*)d_in[8];
  const float* bk = (const float*)d_in[9];
  const float* Wv = (const float*)d_in[10];
  const float* bv = (const float*)d_in[11];
  const float* Wo = (const float*)d_in[12];
  const float* bo = (const float*)d_in[13];

  char* ws = (char*)d_ws;
  unsigned short* xb = (unsigned short*)(ws + 0);          // 26,214,400 (x bf16; later o)
  unsigned short* qb = (unsigned short*)(ws + 26214400);   // 26,214,400
  unsigned short* w1t = (unsigned short*)(ws + 52428800);  // 33,554,432 (w1t; later vT 29,360,128)
  unsigned short* fc2wT = (unsigned short*)(ws + 85983232);  // 16,777,216 (dead before kb)
  unsigned short* kb_ = (unsigned short*)(ws + 85983232);    // 26,214,400 (after meta gemm)
  char* sm = ws + 112197632;
  unsigned short* h1b = (unsigned short*)(sm);             // 65,536
  float* bias2 = (float*)(sm + 65536);                     // 262,144
  unsigned short* wkT = (unsigned short*)(sm + 327680);    // 131,072
  unsigned short* wvT = (unsigned short*)(sm + 458752);    // 131,072
  unsigned short* woT = (unsigned short*)(sm + 589824);    // 131,072
  unsigned short* vT = w1t;  // alias: w1t dead after q gemm
  unsigned short* ob = xb;   // alias: x dead after v gemm

  cast_x_k<<<6400, 256, 0, stream>>>(x, xb);
  hyper_h1<<<256, 128, 0, stream>>>(ue, fc1w, fc1b, h1b);
  prep_wt<<<dim3(256, 3), 256, 0, stream>>>(Wk, Wv, Wo, wkT, wvT, woT);
  prep_fc2<<<dim3(2048, 4), 256, 0, stream>>>(fc2w, fc2b, bw, fc2wT, bias2);
  // meta GEMM: w1t[b][n] = sum_j h1b[b][j]*fc2wT[n][j] + bias2[n]; "batch"=n-tile
  gemm64x256<1, 4><<<1024, 256, 0, stream>>>(h1b, fc2wT, bias2, w1t, B_, HID_, HID_,
                                             D_ * D_, 0L, 256L * HID_, 256L, 256L, 4, 256);
  // q = x @ w1 + b_q (batched over B)
  gemm64x256<1, 8><<<1024, 256, 0, stream>>>(xb, w1t, bq, qb, L_, D_, D_, D_,
                                             (long)L_ * D_, (long)D_ * D_, 0L, (long)L_ * D_,
                                             4, 256);
  // k = x @ Wk + bk (flat)
  gemm64x256<1, 8><<<800, 256, 0, stream>>>(xb, wkT, bk, kb_, B_ * L_, D_, D_, D_,
                                            0L, 0L, 0L, 0L, 800, 1);
  // v = x @ Wv + bv, written transposed -> vT[b][d][m], ld 224
  gemm64x256<2, 8><<<1024, 256, 0, stream>>>(xb, wvT, bv, vT, L_, D_, D_, 224,
                                             (long)L_ * D_, 0L, 0L, 256L * 224L, 4, 256);
  // fused causal attention -> ob
  attn_k<<<dim3(4, H_, B_), 256, 0, stream>>>(qb, kb_, vT, ob);
  // out = o @ Wo + bo -> f32 d_out (flat)
  gemm64x256<0, 8><<<800, 256, 0, stream>>>(ob, woT, bo, d_out, B_ * L_, D_, D_, D_,
                                            0L, 0L, 0L, 0L, 800, 1);
}